// Round 11
// baseline (84.891 us; speedup 1.0000x reference)
//
#include <hip/hip_runtime.h>

#define DEV __device__ __forceinline__

typedef __bf16 bf16;
typedef __bf16 bf16x8 __attribute__((ext_vector_type(8)));
typedef __bf16 bf16x4 __attribute__((ext_vector_type(4)));
typedef float f32x4 __attribute__((ext_vector_type(4)));
typedef float f32x16 __attribute__((ext_vector_type(16)));
typedef unsigned int u32x4 __attribute__((ext_vector_type(4)));

// 1/sqrt(512) * log2(e): scores pre-scaled so softmax uses exp2 directly
#define SCALE_F (0.04419417382415922f * 1.4426950408889634f)

DEV void gload_lds16(const void* g, void* l) {
  __builtin_amdgcn_global_load_lds(
      (const __attribute__((address_space(1))) void*)g,
      (__attribute__((address_space(3))) void*)l, 16, 0, 0);
}

DEV f32x4 mfma16(bf16x8 a, bf16x8 b, f32x4 c) {
  return __builtin_amdgcn_mfma_f32_16x16x32_bf16(a, b, c, 0, 0, 0);
}
DEV f32x16 mfma32(bf16x8 a, bf16x8 b, f32x16 c) {
  return __builtin_amdgcn_mfma_f32_32x32x16_bf16(a, b, c, 0, 0, 0);
}

DEV unsigned int pkbf(float a, float b) {
  unsigned short ua = __builtin_bit_cast(unsigned short, (bf16)a);
  unsigned short ub = __builtin_bit_cast(unsigned short, (bf16)b);
  return (unsigned int)ua | ((unsigned int)ub << 16);
}

// ---------------------------------------------------------------------------
// prep: blocks 0..2047 -> weight prep; blocks 2048..2559 -> Q transpose.
// ---------------------------------------------------------------------------
__global__ __launch_bounds__(256) void prep(
    const float* __restrict__ Q,
    const float* __restrict__ Wq, const float* __restrict__ bq,
    const float* __restrict__ Wk, const float* __restrict__ bk,
    const float* __restrict__ Wv, const float* __restrict__ bv,
    const float* __restrict__ Wo,
    bf16* __restrict__ Wf, float* __restrict__ biasf, bf16* __restrict__ Wor,
    bf16* __restrict__ Qt) {
  __shared__ float tile[64][65];
  int bid = blockIdx.x;
  int t = threadIdx.x;
  if (bid < 2048) {
    int row = bid;
    if (row < 1536) {
      const float* src;
      float scale = 1.0f;
      if (row < 512)       { src = Wq + (size_t)row * 512; scale = SCALE_F; }
      else if (row < 1024) { src = Wk + (size_t)(row - 512) * 512; }
      else                 { src = Wv + (size_t)(row - 1024) * 512; }
      for (int c = t; c < 512; c += 256)
        Wf[(size_t)row * 512 + c] = (bf16)(src[c] * scale);
      if (t == 0) {
        float bb;
        if (row < 512)       bb = bq[row] * SCALE_F;
        else if (row < 1024) bb = bk[row - 512];
        else                 bb = bv[row - 1024];
        biasf[row] = bb;
      }
    } else {
      int r = row - 1536;
      for (int c2 = t; c2 < 512; c2 += 256) {
        int hh = c2 >> 6, dd = c2 & 63;
        Wor[(size_t)r * 512 + c2] = (bf16)Wo[(size_t)r * 512 + dd * 8 + hh];
      }
    }
  } else {
    int id2 = bid - 2048;
    int n0 = (id2 & 31) * 64;
    int d0 = ((id2 >> 5) & 7) * 64;
    int b = id2 >> 8;
    int r = t >> 2, cw = t & 3;
    const float* src = Q + ((size_t)(b * 512 + d0 + r)) * 2048 + n0 + cw * 16;
#pragma unroll
    for (int e4 = 0; e4 < 4; ++e4) {
      float4 v = *(const float4*)(src + e4 * 4);
      tile[r][cw * 16 + e4 * 4 + 0] = v.x;
      tile[r][cw * 16 + e4 * 4 + 1] = v.y;
      tile[r][cw * 16 + e4 * 4 + 2] = v.z;
      tile[r][cw * 16 + e4 * 4 + 3] = v.w;
    }
    __syncthreads();
    bf16x8 o0{}, o1{};
#pragma unroll
    for (int e = 0; e < 8; ++e) {
      o0[e] = (bf16)tile[cw * 16 + e][r];
      o1[e] = (bf16)tile[cw * 16 + 8 + e][r];
    }
    bf16* dst = Qt + ((size_t)(b * 2048 + n0 + r)) * 512 + d0 + cw * 16;
    *(bf16x8*)dst = o0;
    *((bf16x8*)dst + 1) = o1;
  }
}

// ---------------------------------------------------------------------------
// qkv_gemm (R9 form): 128x64 tiles, single-buffer, 2 barriers/K-step.
// grid (12, 32, 2). Epilogue scatters to qp/kp/vn.
// ---------------------------------------------------------------------------
__global__ __launch_bounds__(256) void qkv_gemm(
    const bf16* __restrict__ Wf, const bf16* __restrict__ Qt,
    const float* __restrict__ biasf,
    bf16* __restrict__ qp, bf16* __restrict__ kp, bf16* __restrict__ vn) {
  __shared__ bf16 Al[128 * 32];
  __shared__ bf16 Bl[64 * 32];
  int b = blockIdx.z;
  int c0 = blockIdx.x * 128;
  int p0 = blockIdx.y * 64;
  int tid = threadIdx.x, w = tid >> 6, lane = tid & 63;
  int wm = w >> 1, wn = w & 1;
  int g = lane >> 4, l15 = lane & 15;

  const bf16* Abase = Wf + (size_t)c0 * 512;
  const bf16* Bbase = Qt + ((size_t)b * 2048 + p0) * 512;

  f32x4 acc[4][2] = {};

  for (int ks = 0; ks < 16; ++ks) {
    int k0 = ks * 32;
    __syncthreads();
#pragma unroll
    for (int i = 0; i < 2; ++i) {
      int rowl = w * 32 + i * 16 + (lane >> 2);
      gload_lds16(Abase + (size_t)rowl * 512 + k0 + (lane & 3) * 8,
                  Al + (w * 32 + i * 16) * 32);
    }
    {
      int browl = w * 16 + (lane >> 2);
      gload_lds16(Bbase + (size_t)browl * 512 + k0 + (lane & 3) * 8,
                  Bl + w * 16 * 32);
    }
    __syncthreads();
    bf16x8 a[4], bb[2];
#pragma unroll
    for (int mi = 0; mi < 4; ++mi)
      a[mi] = *(const bf16x8*)(Al + (wm * 64 + mi * 16 + l15) * 32 + g * 8);
#pragma unroll
    for (int ni = 0; ni < 2; ++ni)
      bb[ni] = *(const bf16x8*)(Bl + (wn * 32 + ni * 16 + l15) * 32 + g * 8);
#pragma unroll
    for (int mi = 0; mi < 4; ++mi)
#pragma unroll
      for (int ni = 0; ni < 2; ++ni)
        acc[mi][ni] = mfma16(a[mi], bb[ni], acc[mi][ni]);
  }

#pragma unroll
  for (int mi = 0; mi < 4; ++mi) {
#pragma unroll
    for (int ni = 0; ni < 2; ++ni) {
#pragma unroll
      for (int r = 0; r < 4; ++r) {
        int row = c0 + wm * 64 + mi * 16 + g * 4 + r;
        int p = p0 + wn * 32 + ni * 16 + l15;
        float val = acc[mi][ni][r] + biasf[row];
        bf16 hv = (bf16)val;
        if (row < 512) {
          int c = row;
          qp[(((size_t)b * 8 + (c & 7)) * 2048 + p) * 64 + (c >> 3)] = hv;
        } else if (row < 1024) {
          int c = row - 512;
          kp[(((size_t)b * 8 + (c & 7)) * 2048 + p) * 64 + (c >> 3)] = hv;
        } else {
          int c = row - 1024;
          vn[((size_t)b * 512 + c) * 2048 + p] = hv;
        }
      }
    }
  }
}

// ---------------------------------------------------------------------------
// attn_k v9 (unchanged from R10): 32x32x16 MFMA, P in-register via
// v_permlane32_swap_b32. 8 waves x 32 q-rows, grid (8, 16, NS), TS=32/NS.
// ---------------------------------------------------------------------------
__global__ __launch_bounds__(512, 4) void attn_k(
    const bf16* __restrict__ qp, const bf16* __restrict__ kp,
    const bf16* __restrict__ vn, bf16* __restrict__ Op,
    float* __restrict__ mbuf, float* __restrict__ lbuf, int TS) {
  __shared__ bf16 Ks[2][64 * 64];
  __shared__ bf16 Vs[2][64 * 64];
  int q0 = blockIdx.x * 256;
  int bh = blockIdx.y;            // b*8 + h
  int z = blockIdx.z;             // kv split
  int b = bh >> 3, h = bh & 7;
  int tid = threadIdx.x, w = tid >> 6, lane = tid & 63;
  int l31 = lane & 31, hi = lane >> 5;

  bf16x8 qreg[4];
#pragma unroll
  for (int kd = 0; kd < 4; ++kd)
    qreg[kd] = *(const bf16x8*)(
        qp + ((size_t)bh * 2048 + q0 + w * 32 + l31) * 64 + kd * 16 + hi * 8);

  int krow = tid >> 3;            // 0..63
  int kch = (tid & 7) ^ (krow & 7);

  const bf16* Kall = kp + (size_t)bh * 2048 * 64 + (size_t)z * TS * 4096;
  const bf16* Vall = vn + ((size_t)(b * 512 + h)) * 2048 + (size_t)z * TS * 64;

  gload_lds16(Kall + (size_t)krow * 64 + kch * 8, Ks[0] + w * 512);
  gload_lds16(Vall + (size_t)krow * 16384 + kch * 8, Vs[0] + w * 512);

  f32x16 oacc0 = {}, oacc1 = {};
  float mrow = -1e30f, rs = 0.0f;

  __syncthreads();

  for (int t = 0; t < TS; ++t) {
    int cur = t & 1, nxt = cur ^ 1;
    int tn = (t < TS - 1) ? t + 1 : t;

    gload_lds16(Kall + (size_t)tn * 4096 + (size_t)krow * 64 + kch * 8,
                Ks[nxt] + w * 512);
    gload_lds16(Vall + (size_t)tn * 64 + (size_t)krow * 16384 + kch * 8,
                Vs[nxt] + w * 512);

    f32x16 st0 = {}, st1 = {};
    __builtin_amdgcn_s_setprio(1);
#pragma unroll
    for (int kd = 0; kd < 4; ++kd) {
      int sw = ((kd * 2 + hi) ^ (l31 & 7)) << 3;
      bf16x8 kb0 = *(const bf16x8*)(Ks[cur] + l31 * 64 + sw);
      bf16x8 kb1 = *(const bf16x8*)(Ks[cur] + (32 + l31) * 64 + sw);
      st0 = mfma32(kb0, qreg[kd], st0);
      st1 = mfma32(kb1, qreg[kd], st1);
    }
    __builtin_amdgcn_s_setprio(0);

    float rm = st0[0];
#pragma unroll
    for (int r = 1; r < 16; ++r) rm = fmaxf(rm, st0[r]);
#pragma unroll
    for (int r = 0; r < 16; ++r) rm = fmaxf(rm, st1[r]);
    rm = fmaxf(rm, __shfl_xor(rm, 32));

    if (__any(rm > mrow + 8.0f)) {
      float nm = fmaxf(mrow, rm);
      float esc = __builtin_amdgcn_exp2f(mrow - nm);
      mrow = nm;
      rs *= esc;
#pragma unroll
      for (int r = 0; r < 16; ++r) {
        int ql = (r & 3) + 8 * (r >> 2) + 4 * hi;
        float er = __shfl(esc, ql, 64);
        oacc0[r] *= er;
        oacc1[r] *= er;
      }
    }

    bf16x8 pa[4];
#pragma unroll
    for (int tile = 0; tile < 2; ++tile) {
      float pv[16];
#pragma unroll
      for (int r = 0; r < 16; ++r) {
        float v = __builtin_amdgcn_exp2f((tile ? st1[r] : st0[r]) - mrow);
        pv[r] = v;
        rs += v;
      }
      unsigned int r0d0 = pkbf(pv[0], pv[1]),   r0d1 = pkbf(pv[2], pv[3]);
      unsigned int r1d0 = pkbf(pv[4], pv[5]),   r1d1 = pkbf(pv[6], pv[7]);
      unsigned int r2d0 = pkbf(pv[8], pv[9]),   r2d1 = pkbf(pv[10], pv[11]);
      unsigned int r3d0 = pkbf(pv[12], pv[13]), r3d1 = pkbf(pv[14], pv[15]);
      asm volatile("v_permlane32_swap_b32 %0, %1" : "+v"(r0d0), "+v"(r1d0));
      asm volatile("v_permlane32_swap_b32 %0, %1" : "+v"(r0d1), "+v"(r1d1));
      pa[tile * 2] = __builtin_bit_cast(bf16x8, (u32x4){r0d0, r0d1, r1d0, r1d1});
      asm volatile("v_permlane32_swap_b32 %0, %1" : "+v"(r2d0), "+v"(r3d0));
      asm volatile("v_permlane32_swap_b32 %0, %1" : "+v"(r2d1), "+v"(r3d1));
      pa[tile * 2 + 1] =
          __builtin_bit_cast(bf16x8, (u32x4){r2d0, r2d1, r3d0, r3d1});
    }

    __builtin_amdgcn_s_setprio(1);
#pragma unroll
    for (int kt = 0; kt < 4; ++kt) {
      int sw0 = ((kt * 2 + hi) ^ (l31 & 7)) << 3;
      bf16x8 vb0 = *(const bf16x8*)(Vs[cur] + l31 * 64 + sw0);
      bf16x8 vb1 = *(const bf16x8*)(Vs[cur] + (32 + l31) * 64 + sw0);
      oacc0 = mfma32(pa[kt], vb0, oacc0);
      oacc1 = mfma32(pa[kt], vb1, oacc1);
    }
    __builtin_amdgcn_s_setprio(0);

    __syncthreads();
  }

  rs += __shfl_xor(rs, 32);

  size_t zb = (size_t)(z * 16 + bh) * 2048 + q0 + w * 32;
#pragma unroll
  for (int r = 0; r < 16; ++r) {
    int ql = (r & 3) + 8 * (r >> 2) + 4 * hi;
    Op[(zb + ql) * 64 + l31] = (bf16)oacc0[r];
    Op[(zb + ql) * 64 + 32 + l31] = (bf16)oacc1[r];
  }
  if (hi == 0) {
    mbuf[zb + l31] = mrow;
    lbuf[zb + l31] = rs;
  }
}

// ---------------------------------------------------------------------------
// outc: out_gemm with combine FUSED into B staging.
// out[b][r][p] = sum_{h,d} Wor[r][h*64+d] * ohC[b][h][p][d] + bo[r]
// where ohC = sum_z (wz/L) * Opart_z  (per-row weights cached in LDS).
// 256 blocks (1-D), XCD swizzle: 4 r-tiles sharing a B strip get bids
// == same mod 8 -> same XCD -> Opart strip stays L2-hot across r-tiles.
// 128x64 tile, BK=32, 4 waves 2x2. A via gload_lds; B reg-staged.
// ---------------------------------------------------------------------------
__global__ __launch_bounds__(256) void outc(
    const bf16* __restrict__ Wor, const bf16* __restrict__ Op,
    const float* __restrict__ mbuf, const float* __restrict__ lbuf,
    const float* __restrict__ bo, float* __restrict__ out, int NS) {
  __shared__ bf16 Al[128 * 32];
  __shared__ bf16 Bl[64 * 32];
  __shared__ float wls[512][4];   // [(h<<6)|p_local][z] = wz/L

  int bid = blockIdx.x;
  int rx = (bid >> 3) & 3;                 // r-tile
  int yz = (bid & 7) + 8 * (bid >> 5);     // 0..63 -> (p-tile, b)
  int r0 = rx * 128;
  int p0 = (yz & 31) * 64;
  int b = yz >> 5;

  int tid = threadIdx.x, w = tid >> 6, lane = tid & 63;
  int wm = w >> 1, wn = w & 1;
  int g = lane >> 4, l15 = lane & 15;

  // weight pre-pass: 512 (h, p_local) pairs
#pragma unroll
  for (int it = 0; it < 2; ++it) {
    int pr = tid + it * 256;
    int hh = pr >> 6, pl = pr & 63;
    size_t row = ((size_t)(b * 8 + hh)) * 2048 + p0 + pl;
    float mz[4], lz[4];
    float M = -1e30f;
    for (int z = 0; z < NS; ++z) {
      mz[z] = mbuf[(size_t)z * 32768 + row];
      lz[z] = lbuf[(size_t)z * 32768 + row];
      M = fmaxf(M, mz[z]);
    }
    float L = 0.0f;
    for (int z = 0; z < NS; ++z) {
      float wz = __builtin_amdgcn_exp2f(mz[z] - M);
      mz[z] = wz;              // reuse as weight
      L += wz * lz[z];
    }
    float invL = 1.0f / L;
    for (int z = 0; z < NS; ++z) wls[pr][z] = mz[z] * invL;
  }

  const bf16* Abase = Wor + (size_t)r0 * 512;

  int browl = w * 16 + (lane >> 2);   // 0..63: B row (p-local)
  int ch8 = (lane & 3) * 8;           // d-chunk

  f32x4 acc[4][2] = {};

  for (int ks = 0; ks < 16; ++ks) {
    int k0 = ks * 32;
    int hh = k0 >> 6, d0 = k0 & 63;
    __syncthreads();
    // A: global -> LDS direct
#pragma unroll
    for (int i = 0; i < 2; ++i) {
      int rowl = w * 32 + i * 16 + (lane >> 2);
      gload_lds16(Abase + (size_t)rowl * 512 + k0 + (lane & 3) * 8,
                  Al + (w * 32 + i * 16) * 32);
    }
    // B: weighted z-sum in registers -> LDS
    {
      size_t base = ((size_t)(b * 8 + hh)) * 2048 + p0 + browl;
      float facc[8];
#pragma unroll
      for (int e = 0; e < 8; ++e) facc[e] = 0.0f;
      for (int z = 0; z < NS; ++z) {
        bf16x8 v = *(const bf16x8*)(Op + ((size_t)z * 32768 + base) * 64 +
                                    d0 + ch8);
        float wz = wls[(hh << 6) | browl][z];
#pragma unroll
        for (int e = 0; e < 8; ++e) facc[e] += wz * (float)v[e];
      }
      bf16x8 pk;
#pragma unroll
      for (int e = 0; e < 8; ++e) pk[e] = (bf16)facc[e];
      *(bf16x8*)(Bl + browl * 32 + ch8) = pk;
    }
    __syncthreads();
    bf16x8 a[4], bb[2];
#pragma unroll
    for (int mi = 0; mi < 4; ++mi)
      a[mi] = *(const bf16x8*)(Al + (wm * 64 + mi * 16 + l15) * 32 + g * 8);
#pragma unroll
    for (int ni = 0; ni < 2; ++ni)
      bb[ni] = *(const bf16x8*)(Bl + (wn * 32 + ni * 16 + l15) * 32 + g * 8);
#pragma unroll
    for (int mi = 0; mi < 4; ++mi)
#pragma unroll
      for (int ni = 0; ni < 2; ++ni)
        acc[mi][ni] = mfma16(a[mi], bb[ni], acc[mi][ni]);
  }

#pragma unroll
  for (int mi = 0; mi < 4; ++mi) {
#pragma unroll
    for (int ni = 0; ni < 2; ++ni) {
#pragma unroll
      for (int r = 0; r < 4; ++r) {
        int row = r0 + wm * 64 + mi * 16 + g * 4 + r;
        int p = p0 + wn * 32 + ni * 16 + l15;
        out[((size_t)b * 512 + row) * 2048 + p] = acc[mi][ni][r] + bo[row];
      }
    }
  }
}

// ---------------------------------------------------------------------------
extern "C" void kernel_launch(void* const* d_in, const int* in_sizes, int n_in,
                              void* d_out, int out_size, void* d_ws, size_t ws_size,
                              hipStream_t stream) {
  (void)in_sizes; (void)n_in; (void)out_size;
  const float* Q  = (const float*)d_in[0];
  const float* Wq = (const float*)d_in[1];
  const float* bq = (const float*)d_in[2];
  const float* Wk = (const float*)d_in[3];
  const float* bk = (const float*)d_in[4];
  const float* Wv = (const float*)d_in[5];
  const float* bv = (const float*)d_in[6];
  const float* Wo = (const float*)d_in[7];
  const float* bo = (const float*)d_in[8];
  float* out = (float*)d_out;

  char* ws = (char*)d_ws;
  bf16*  Wf    = (bf16*)(ws + 0);          // 1536*512*2  = 1572864
  bf16*  Wor   = (bf16*)(ws + 1572864);    // 512*512*2   = 524288
  float* biasf = (float*)(ws + 2097152);   // 1536*4      = 6144
  bf16*  Qt    = (bf16*)(ws + 2103296);    // 2*2048*512*2 = 4194304
  bf16*  qp    = (bf16*)(ws + 6297600);    // 4194304
  bf16*  kp    = (bf16*)(ws + 10491904);   // 4194304
  bf16*  vn    = (bf16*)(ws + 14686208);   // 4194304 (ends 18880512)

  size_t need4 = 18880512ull + 4ull * 4194304 + 2ull * 4ull * 131072;
  int NS = (ws_size >= need4) ? 4 : 2;
  int TS = 32 / NS;

  bf16*  Opart = (bf16*)(ws + 18880512);               // NS * 4194304 bytes
  float* mbuf  = (float*)(ws + 18880512 + (size_t)NS * 4194304);
  float* lbuf  = (float*)(ws + 18880512 + (size_t)NS * 4194304 +
                          (size_t)NS * 131072);

  prep<<<dim3(2560), dim3(256), 0, stream>>>(Q, Wq, bq, Wk, bk, Wv, bv, Wo,
                                             Wf, biasf, Wor, Qt);
  qkv_gemm<<<dim3(12, 32, 2), dim3(256), 0, stream>>>(Wf, Qt, biasf, qp, kp, vn);
  attn_k<<<dim3(8, 16, NS), dim3(512), 0, stream>>>(qp, kp, vn, Opart, mbuf,
                                                    lbuf, TS);
  outc<<<dim3(256), dim3(256), 0, stream>>>(Wor, Opart, mbuf, lbuf, bo, out, NS);
}

// Round 12
// 75.688 us; speedup vs baseline: 1.1216x; 1.1216x over previous
//
#include <hip/hip_runtime.h>

#define DEV __device__ __forceinline__

typedef __bf16 bf16;
typedef __bf16 bf16x8 __attribute__((ext_vector_type(8)));
typedef __bf16 bf16x4 __attribute__((ext_vector_type(4)));
typedef float f32x4 __attribute__((ext_vector_type(4)));
typedef float f32x16 __attribute__((ext_vector_type(16)));
typedef unsigned int u32x4 __attribute__((ext_vector_type(4)));

// 1/sqrt(512) * log2(e): scores pre-scaled so softmax uses exp2 directly
#define SCALE_F (0.04419417382415922f * 1.4426950408889634f)

DEV void gload_lds16(const void* g, void* l) {
  __builtin_amdgcn_global_load_lds(
      (const __attribute__((address_space(1))) void*)g,
      (__attribute__((address_space(3))) void*)l, 16, 0, 0);
}

DEV f32x4 mfma16(bf16x8 a, bf16x8 b, f32x4 c) {
  return __builtin_amdgcn_mfma_f32_16x16x32_bf16(a, b, c, 0, 0, 0);
}
DEV f32x16 mfma32(bf16x8 a, bf16x8 b, f32x16 c) {
  return __builtin_amdgcn_mfma_f32_32x32x16_bf16(a, b, c, 0, 0, 0);
}

DEV unsigned int pkbf(float a, float b) {
  unsigned short ua = __builtin_bit_cast(unsigned short, (bf16)a);
  unsigned short ub = __builtin_bit_cast(unsigned short, (bf16)b);
  return (unsigned int)ua | ((unsigned int)ub << 16);
}

// ---------------------------------------------------------------------------
// prep: blocks 0..2047 -> weight prep; blocks 2048..2559 -> Q transpose.
// ---------------------------------------------------------------------------
__global__ __launch_bounds__(256) void prep(
    const float* __restrict__ Q,
    const float* __restrict__ Wq, const float* __restrict__ bq,
    const float* __restrict__ Wk, const float* __restrict__ bk,
    const float* __restrict__ Wv, const float* __restrict__ bv,
    const float* __restrict__ Wo,
    bf16* __restrict__ Wf, float* __restrict__ biasf, bf16* __restrict__ Wor,
    bf16* __restrict__ Qt) {
  __shared__ float tile[64][65];
  int bid = blockIdx.x;
  int t = threadIdx.x;
  if (bid < 2048) {
    int row = bid;
    if (row < 1536) {
      const float* src;
      float scale = 1.0f;
      if (row < 512)       { src = Wq + (size_t)row * 512; scale = SCALE_F; }
      else if (row < 1024) { src = Wk + (size_t)(row - 512) * 512; }
      else                 { src = Wv + (size_t)(row - 1024) * 512; }
      for (int c = t; c < 512; c += 256)
        Wf[(size_t)row * 512 + c] = (bf16)(src[c] * scale);
      if (t == 0) {
        float bb;
        if (row < 512)       bb = bq[row] * SCALE_F;
        else if (row < 1024) bb = bk[row - 512];
        else                 bb = bv[row - 1024];
        biasf[row] = bb;
      }
    } else {
      int r = row - 1536;
      for (int c2 = t; c2 < 512; c2 += 256) {
        int hh = c2 >> 6, dd = c2 & 63;
        Wor[(size_t)r * 512 + c2] = (bf16)Wo[(size_t)r * 512 + dd * 8 + hh];
      }
    }
  } else {
    int id2 = bid - 2048;
    int n0 = (id2 & 31) * 64;
    int d0 = ((id2 >> 5) & 7) * 64;
    int b = id2 >> 8;
    int r = t >> 2, cw = t & 3;
    const float* src = Q + ((size_t)(b * 512 + d0 + r)) * 2048 + n0 + cw * 16;
#pragma unroll
    for (int e4 = 0; e4 < 4; ++e4) {
      float4 v = *(const float4*)(src + e4 * 4);
      tile[r][cw * 16 + e4 * 4 + 0] = v.x;
      tile[r][cw * 16 + e4 * 4 + 1] = v.y;
      tile[r][cw * 16 + e4 * 4 + 2] = v.z;
      tile[r][cw * 16 + e4 * 4 + 3] = v.w;
    }
    __syncthreads();
    bf16x8 o0{}, o1{};
#pragma unroll
    for (int e = 0; e < 8; ++e) {
      o0[e] = (bf16)tile[cw * 16 + e][r];
      o1[e] = (bf16)tile[cw * 16 + 8 + e][r];
    }
    bf16* dst = Qt + ((size_t)(b * 2048 + n0 + r)) * 512 + d0 + cw * 16;
    *(bf16x8*)dst = o0;
    *((bf16x8*)dst + 1) = o1;
  }
}

// ---------------------------------------------------------------------------
// qkv_gemm v4: 128x64 tile, BK=64 (8 K-steps, 16 barriers instead of 32).
// Rows are 128B -> XOR-chunk swizzle (pre-swizzled source, swizzled reads).
// grid (12, 32, 2) = 768 blocks = 3/CU even. 4 waves 2x2.
// C[c][p] = sum_k Wf[c][k] * Qt[b][p][k] + bias[c]
// Epilogue: c<512 -> qp[b][h][p][d]; c<1024 -> kp; else vn[b][c][p]
// ---------------------------------------------------------------------------
__global__ __launch_bounds__(256) void qkv_gemm(
    const bf16* __restrict__ Wf, const bf16* __restrict__ Qt,
    const float* __restrict__ biasf,
    bf16* __restrict__ qp, bf16* __restrict__ kp, bf16* __restrict__ vn) {
  __shared__ bf16 Al[128 * 64];
  __shared__ bf16 Bl[64 * 64];
  int b = blockIdx.z;
  int c0 = blockIdx.x * 128;
  int p0 = blockIdx.y * 64;
  int tid = threadIdx.x, w = tid >> 6, lane = tid & 63;
  int wm = w >> 1, wn = w & 1;
  int g = lane >> 4, l15 = lane & 15;

  const bf16* Abase = Wf + (size_t)c0 * 512;
  const bf16* Bbase = Qt + ((size_t)b * 2048 + p0) * 512;

  int srow = tid >> 3;           // 0..31 (+i*32)
  int sch = tid & 7;

  f32x4 acc[4][2] = {};

  for (int ks = 0; ks < 8; ++ks) {
    int k0 = ks * 64;
    __syncthreads();
    // A: 128 rows x 128B = 4 issues; swizzled source chunk, linear dest
#pragma unroll
    for (int i = 0; i < 4; ++i) {
      int row = srow + i * 32;
      int ch = sch ^ (row & 7);
      gload_lds16(Abase + (size_t)row * 512 + k0 + ch * 8,
                  Al + (i * 32 + w * 8) * 64);
    }
    // B: 64 rows x 128B = 2 issues
#pragma unroll
    for (int i = 0; i < 2; ++i) {
      int row = srow + i * 32;
      int ch = sch ^ (row & 7);
      gload_lds16(Bbase + (size_t)row * 512 + k0 + ch * 8,
                  Bl + (i * 32 + w * 8) * 64);
    }
    __syncthreads();
#pragma unroll
    for (int ks2 = 0; ks2 < 2; ++ks2) {
      bf16x8 a[4], bb[2];
#pragma unroll
      for (int mi = 0; mi < 4; ++mi) {
        int row = wm * 64 + mi * 16 + l15;
        a[mi] = *(const bf16x8*)(Al + row * 64 +
                                 (((ks2 * 4 + g) ^ (row & 7)) << 3));
      }
#pragma unroll
      for (int ni = 0; ni < 2; ++ni) {
        int row = wn * 32 + ni * 16 + l15;
        bb[ni] = *(const bf16x8*)(Bl + row * 64 +
                                  (((ks2 * 4 + g) ^ (row & 7)) << 3));
      }
#pragma unroll
      for (int mi = 0; mi < 4; ++mi)
#pragma unroll
        for (int ni = 0; ni < 2; ++ni)
          acc[mi][ni] = mfma16(a[mi], bb[ni], acc[mi][ni]);
    }
  }

#pragma unroll
  for (int mi = 0; mi < 4; ++mi) {
#pragma unroll
    for (int ni = 0; ni < 2; ++ni) {
#pragma unroll
      for (int r = 0; r < 4; ++r) {
        int row = c0 + wm * 64 + mi * 16 + g * 4 + r;
        int p = p0 + wn * 32 + ni * 16 + l15;
        float val = acc[mi][ni][r] + biasf[row];
        bf16 hv = (bf16)val;
        if (row < 512) {
          int c = row;
          qp[(((size_t)b * 8 + (c & 7)) * 2048 + p) * 64 + (c >> 3)] = hv;
        } else if (row < 1024) {
          int c = row - 512;
          kp[(((size_t)b * 8 + (c & 7)) * 2048 + p) * 64 + (c >> 3)] = hv;
        } else {
          int c = row - 1024;
          vn[((size_t)b * 512 + c) * 2048 + p] = hv;
        }
      }
    }
  }
}

// ---------------------------------------------------------------------------
// attn_k v9 (unchanged from R10): 32x32x16 MFMA, P in-register via
// v_permlane32_swap_b32. 8 waves x 32 q-rows, grid (8, 16, NS), TS=32/NS.
// ---------------------------------------------------------------------------
__global__ __launch_bounds__(512, 4) void attn_k(
    const bf16* __restrict__ qp, const bf16* __restrict__ kp,
    const bf16* __restrict__ vn, bf16* __restrict__ Op,
    float* __restrict__ mbuf, float* __restrict__ lbuf, int TS) {
  __shared__ bf16 Ks[2][64 * 64];
  __shared__ bf16 Vs[2][64 * 64];
  int q0 = blockIdx.x * 256;
  int bh = blockIdx.y;            // b*8 + h
  int z = blockIdx.z;             // kv split
  int b = bh >> 3, h = bh & 7;
  int tid = threadIdx.x, w = tid >> 6, lane = tid & 63;
  int l31 = lane & 31, hi = lane >> 5;

  bf16x8 qreg[4];
#pragma unroll
  for (int kd = 0; kd < 4; ++kd)
    qreg[kd] = *(const bf16x8*)(
        qp + ((size_t)bh * 2048 + q0 + w * 32 + l31) * 64 + kd * 16 + hi * 8);

  int krow = tid >> 3;            // 0..63
  int kch = (tid & 7) ^ (krow & 7);

  const bf16* Kall = kp + (size_t)bh * 2048 * 64 + (size_t)z * TS * 4096;
  const bf16* Vall = vn + ((size_t)(b * 512 + h)) * 2048 + (size_t)z * TS * 64;

  gload_lds16(Kall + (size_t)krow * 64 + kch * 8, Ks[0] + w * 512);
  gload_lds16(Vall + (size_t)krow * 16384 + kch * 8, Vs[0] + w * 512);

  f32x16 oacc0 = {}, oacc1 = {};
  float mrow = -1e30f, rs = 0.0f;

  __syncthreads();

  for (int t = 0; t < TS; ++t) {
    int cur = t & 1, nxt = cur ^ 1;
    int tn = (t < TS - 1) ? t + 1 : t;

    gload_lds16(Kall + (size_t)tn * 4096 + (size_t)krow * 64 + kch * 8,
                Ks[nxt] + w * 512);
    gload_lds16(Vall + (size_t)tn * 64 + (size_t)krow * 16384 + kch * 8,
                Vs[nxt] + w * 512);

    f32x16 st0 = {}, st1 = {};
    __builtin_amdgcn_s_setprio(1);
#pragma unroll
    for (int kd = 0; kd < 4; ++kd) {
      int sw = ((kd * 2 + hi) ^ (l31 & 7)) << 3;
      bf16x8 kb0 = *(const bf16x8*)(Ks[cur] + l31 * 64 + sw);
      bf16x8 kb1 = *(const bf16x8*)(Ks[cur] + (32 + l31) * 64 + sw);
      st0 = mfma32(kb0, qreg[kd], st0);
      st1 = mfma32(kb1, qreg[kd], st1);
    }
    __builtin_amdgcn_s_setprio(0);

    float rm = st0[0];
#pragma unroll
    for (int r = 1; r < 16; ++r) rm = fmaxf(rm, st0[r]);
#pragma unroll
    for (int r = 0; r < 16; ++r) rm = fmaxf(rm, st1[r]);
    rm = fmaxf(rm, __shfl_xor(rm, 32));

    if (__any(rm > mrow + 8.0f)) {
      float nm = fmaxf(mrow, rm);
      float esc = __builtin_amdgcn_exp2f(mrow - nm);
      mrow = nm;
      rs *= esc;
#pragma unroll
      for (int r = 0; r < 16; ++r) {
        int ql = (r & 3) + 8 * (r >> 2) + 4 * hi;
        float er = __shfl(esc, ql, 64);
        oacc0[r] *= er;
        oacc1[r] *= er;
      }
    }

    bf16x8 pa[4];
#pragma unroll
    for (int tile = 0; tile < 2; ++tile) {
      float pv[16];
#pragma unroll
      for (int r = 0; r < 16; ++r) {
        float v = __builtin_amdgcn_exp2f((tile ? st1[r] : st0[r]) - mrow);
        pv[r] = v;
        rs += v;
      }
      unsigned int r0d0 = pkbf(pv[0], pv[1]),   r0d1 = pkbf(pv[2], pv[3]);
      unsigned int r1d0 = pkbf(pv[4], pv[5]),   r1d1 = pkbf(pv[6], pv[7]);
      unsigned int r2d0 = pkbf(pv[8], pv[9]),   r2d1 = pkbf(pv[10], pv[11]);
      unsigned int r3d0 = pkbf(pv[12], pv[13]), r3d1 = pkbf(pv[14], pv[15]);
      asm volatile("v_permlane32_swap_b32 %0, %1" : "+v"(r0d0), "+v"(r1d0));
      asm volatile("v_permlane32_swap_b32 %0, %1" : "+v"(r0d1), "+v"(r1d1));
      pa[tile * 2] = __builtin_bit_cast(bf16x8, (u32x4){r0d0, r0d1, r1d0, r1d1});
      asm volatile("v_permlane32_swap_b32 %0, %1" : "+v"(r2d0), "+v"(r3d0));
      asm volatile("v_permlane32_swap_b32 %0, %1" : "+v"(r2d1), "+v"(r3d1));
      pa[tile * 2 + 1] =
          __builtin_bit_cast(bf16x8, (u32x4){r2d0, r2d1, r3d0, r3d1});
    }

    __builtin_amdgcn_s_setprio(1);
#pragma unroll
    for (int kt = 0; kt < 4; ++kt) {
      int sw0 = ((kt * 2 + hi) ^ (l31 & 7)) << 3;
      bf16x8 vb0 = *(const bf16x8*)(Vs[cur] + l31 * 64 + sw0);
      bf16x8 vb1 = *(const bf16x8*)(Vs[cur] + (32 + l31) * 64 + sw0);
      oacc0 = mfma32(pa[kt], vb0, oacc0);
      oacc1 = mfma32(pa[kt], vb1, oacc1);
    }
    __builtin_amdgcn_s_setprio(0);

    __syncthreads();
  }

  rs += __shfl_xor(rs, 32);

  size_t zb = (size_t)(z * 16 + bh) * 2048 + q0 + w * 32;
#pragma unroll
  for (int r = 0; r < 16; ++r) {
    int ql = (r & 3) + 8 * (r >> 2) + 4 * hi;
    Op[(zb + ql) * 64 + l31] = (bf16)oacc0[r];
    Op[(zb + ql) * 64 + 32 + l31] = (bf16)oacc1[r];
  }
  if (hi == 0) {
    mbuf[zb + l31] = mrow;
    lbuf[zb + l31] = rs;
  }
}

// ---------------------------------------------------------------------------
// combine (R10 form): oh[row][d] = sum_z wz*O_z / sum_z wz*l_z.
// oh ALIASES Op[z=0] (each thread reads only its own slice -> race-free).
// ---------------------------------------------------------------------------
__global__ __launch_bounds__(256) void combine(
    const bf16* __restrict__ Op, const float* __restrict__ mbuf,
    const float* __restrict__ lbuf, bf16* __restrict__ oh, int NS) {
  int idx = blockIdx.x * 256 + threadIdx.x;
  int row = idx >> 2;
  int dc = (idx & 3) * 16;

  float M = -1e30f;
  for (int z = 0; z < NS; ++z) M = fmaxf(M, mbuf[(size_t)z * 32768 + row]);

  float L = 0.0f;
  float acc[16];
#pragma unroll
  for (int e = 0; e < 16; ++e) acc[e] = 0.0f;

  for (int z = 0; z < NS; ++z) {
    float wz = __builtin_amdgcn_exp2f(mbuf[(size_t)z * 32768 + row] - M);
    L += wz * lbuf[(size_t)z * 32768 + row];
    const bf16x8* p = (const bf16x8*)(Op + ((size_t)z * 32768 + row) * 64 + dc);
#pragma unroll
    for (int v = 0; v < 2; ++v) {
      bf16x8 x = p[v];
#pragma unroll
      for (int e = 0; e < 8; ++e) acc[v * 8 + e] += wz * (float)x[e];
    }
  }
  float invL = 1.0f / L;
  bf16x8* po = (bf16x8*)(oh + (size_t)row * 64 + dc);
#pragma unroll
  for (int v = 0; v < 2; ++v) {
    bf16x8 o;
#pragma unroll
    for (int e = 0; e < 8; ++e) o[e] = (bf16)(acc[v * 8 + e] * invL);
    po[v] = o;
  }
}

// ---------------------------------------------------------------------------
// out_gemm v4: 128x64 tile, BK=64 (one head per K-step). 8 steps.
// XOR-chunk swizzle on both tiles. grid (4, 32, 2).
// out[b][r][p] = sum_k Wor[r][k] * oh_as_B[p][k] + bo[r]   (fp32 out)
// ---------------------------------------------------------------------------
__global__ __launch_bounds__(256) void out_gemm(
    const bf16* __restrict__ Wor, const bf16* __restrict__ oh,
    const float* __restrict__ bo, float* __restrict__ out) {
  __shared__ bf16 Al[128 * 64];
  __shared__ bf16 Bl[64 * 64];
  int b = blockIdx.z;
  int r0 = blockIdx.x * 128;
  int p0 = blockIdx.y * 64;
  int tid = threadIdx.x, w = tid >> 6, lane = tid & 63;
  int wm = w >> 1, wn = w & 1;
  int g = lane >> 4, l15 = lane & 15;

  const bf16* Abase = Wor + (size_t)r0 * 512;

  int srow = tid >> 3;
  int sch = tid & 7;

  f32x4 acc[4][2] = {};

  for (int ks = 0; ks < 8; ++ks) {
    int k0 = ks * 64;
    // B rows for head ks: oh[(b*8+ks)*2048 + p0 + row][0..63]
    const bf16* Bbase = oh + (((size_t)b * 8 + ks) * 2048 + p0) * 64;
    __syncthreads();
#pragma unroll
    for (int i = 0; i < 4; ++i) {
      int row = srow + i * 32;
      int ch = sch ^ (row & 7);
      gload_lds16(Abase + (size_t)row * 512 + k0 + ch * 8,
                  Al + (i * 32 + w * 8) * 64);
    }
#pragma unroll
    for (int i = 0; i < 2; ++i) {
      int row = srow + i * 32;
      int ch = sch ^ (row & 7);
      gload_lds16(Bbase + (size_t)row * 64 + ch * 8,
                  Bl + (i * 32 + w * 8) * 64);
    }
    __syncthreads();
#pragma unroll
    for (int ks2 = 0; ks2 < 2; ++ks2) {
      bf16x8 a[4], bb[2];
#pragma unroll
      for (int mi = 0; mi < 4; ++mi) {
        int row = wm * 64 + mi * 16 + l15;
        a[mi] = *(const bf16x8*)(Al + row * 64 +
                                 (((ks2 * 4 + g) ^ (row & 7)) << 3));
      }
#pragma unroll
      for (int ni = 0; ni < 2; ++ni) {
        int row = wn * 32 + ni * 16 + l15;
        bb[ni] = *(const bf16x8*)(Bl + row * 64 +
                                  (((ks2 * 4 + g) ^ (row & 7)) << 3));
      }
#pragma unroll
      for (int mi = 0; mi < 4; ++mi)
#pragma unroll
        for (int ni = 0; ni < 2; ++ni)
          acc[mi][ni] = mfma16(a[mi], bb[ni], acc[mi][ni]);
    }
  }

#pragma unroll
  for (int mi = 0; mi < 4; ++mi) {
#pragma unroll
    for (int ni = 0; ni < 2; ++ni) {
#pragma unroll
      for (int r = 0; r < 4; ++r) {
        int row = r0 + wm * 64 + mi * 16 + g * 4 + r;
        int p = p0 + wn * 32 + ni * 16 + l15;
        out[((size_t)b * 512 + row) * 2048 + p] = acc[mi][ni][r] + bo[row];
      }
    }
  }
}

// ---------------------------------------------------------------------------
extern "C" void kernel_launch(void* const* d_in, const int* in_sizes, int n_in,
                              void* d_out, int out_size, void* d_ws, size_t ws_size,
                              hipStream_t stream) {
  (void)in_sizes; (void)n_in; (void)out_size;
  const float* Q  = (const float*)d_in[0];
  const float* Wq = (const float*)d_in[1];
  const float* bq = (const float*)d_in[2];
  const float* Wk = (const float*)d_in[3];
  const float* bk = (const float*)d_in[4];
  const float* Wv = (const float*)d_in[5];
  const float* bv = (const float*)d_in[6];
  const float* Wo = (const float*)d_in[7];
  const float* bo = (const float*)d_in[8];
  float* out = (float*)d_out;

  char* ws = (char*)d_ws;
  bf16*  Wf    = (bf16*)(ws + 0);          // 1536*512*2  = 1572864
  bf16*  Wor   = (bf16*)(ws + 1572864);    // 512*512*2   = 524288
  float* biasf = (float*)(ws + 2097152);   // 1536*4      = 6144
  bf16*  Qt    = (bf16*)(ws + 2103296);    // 2*2048*512*2 = 4194304
  bf16*  qp    = (bf16*)(ws + 6297600);    // 4194304
  bf16*  kp    = (bf16*)(ws + 10491904);   // 4194304
  bf16*  vn    = (bf16*)(ws + 14686208);   // 4194304 (ends 18880512)

  size_t need4 = 18880512ull + 4ull * 4194304 + 2ull * 4ull * 131072;
  int NS = (ws_size >= need4) ? 4 : 2;
  int TS = 32 / NS;

  bf16*  Opart = (bf16*)(ws + 18880512);               // NS * 4194304 bytes
  float* mbuf  = (float*)(ws + 18880512 + (size_t)NS * 4194304);
  float* lbuf  = (float*)(ws + 18880512 + (size_t)NS * 4194304 +
                          (size_t)NS * 131072);
  bf16*  oh    = Opart;  // combine writes in place over z=0 (race-free)

  prep<<<dim3(2560), dim3(256), 0, stream>>>(Q, Wq, bq, Wk, bk, Wv, bv, Wo,
                                             Wf, biasf, Wor, Qt);
  qkv_gemm<<<dim3(12, 32, 2), dim3(256), 0, stream>>>(Wf, Qt, biasf, qp, kp, vn);
  attn_k<<<dim3(8, 16, NS), dim3(512), 0, stream>>>(qp, kp, vn, Opart, mbuf,
                                                    lbuf, TS);
  combine<<<dim3(512), dim3(256), 0, stream>>>(Opart, mbuf, lbuf, oh, NS);
  out_gemm<<<dim3(4, 32, 2), dim3(256), 0, stream>>>(Wor, oh, bo, out);
}

// Round 13
// 73.053 us; speedup vs baseline: 1.1620x; 1.0361x over previous
//
#include <hip/hip_runtime.h>

#define DEV __device__ __forceinline__

typedef __bf16 bf16;
typedef __bf16 bf16x8 __attribute__((ext_vector_type(8)));
typedef __bf16 bf16x4 __attribute__((ext_vector_type(4)));
typedef float f32x4 __attribute__((ext_vector_type(4)));
typedef float f32x16 __attribute__((ext_vector_type(16)));
typedef unsigned int u32x4 __attribute__((ext_vector_type(4)));

// 1/sqrt(512) * log2(e): scores pre-scaled so softmax uses exp2 directly
#define SCALE_F (0.04419417382415922f * 1.4426950408889634f)

DEV void gload_lds16(const void* g, void* l) {
  __builtin_amdgcn_global_load_lds(
      (const __attribute__((address_space(1))) void*)g,
      (__attribute__((address_space(3))) void*)l, 16, 0, 0);
}

DEV f32x4 mfma16(bf16x8 a, bf16x8 b, f32x4 c) {
  return __builtin_amdgcn_mfma_f32_16x16x32_bf16(a, b, c, 0, 0, 0);
}
DEV f32x16 mfma32(bf16x8 a, bf16x8 b, f32x16 c) {
  return __builtin_amdgcn_mfma_f32_32x32x16_bf16(a, b, c, 0, 0, 0);
}

DEV unsigned int pkbf(float a, float b) {
  unsigned short ua = __builtin_bit_cast(unsigned short, (bf16)a);
  unsigned short ub = __builtin_bit_cast(unsigned short, (bf16)b);
  return (unsigned int)ua | ((unsigned int)ub << 16);
}

// ---------------------------------------------------------------------------
// prep v2: blocks 0..255 -> weight prep (8 rows each, coalesced float4);
//          blocks 256..767 -> Q transpose (64x64 tiles).
// ---------------------------------------------------------------------------
__global__ __launch_bounds__(256) void prep(
    const float* __restrict__ Q,
    const float* __restrict__ Wq, const float* __restrict__ bq,
    const float* __restrict__ Wk, const float* __restrict__ bk,
    const float* __restrict__ Wv, const float* __restrict__ bv,
    const float* __restrict__ Wo,
    bf16* __restrict__ Wf, float* __restrict__ biasf, bf16* __restrict__ Wor,
    bf16* __restrict__ Qt) {
  __shared__ float tile[64][65];
  int bid = blockIdx.x;
  int t = threadIdx.x;
  if (bid < 256) {
    int r0 = bid * 8;
    for (int idx = t; idx < 1024; idx += 256) {  // 8 rows x 128 float4
      int rl = idx >> 7, c4 = idx & 127;
      int row = r0 + rl;
      if (row < 1536) {
        const float* src;
        float scale = 1.0f;
        if (row < 512)       { src = Wq + (size_t)row * 512; scale = SCALE_F; }
        else if (row < 1024) { src = Wk + (size_t)(row - 512) * 512; }
        else                 { src = Wv + (size_t)(row - 1024) * 512; }
        float4 v = ((const float4*)src)[c4];
        bf16x4 o;
        o[0] = (bf16)(v.x * scale);
        o[1] = (bf16)(v.y * scale);
        o[2] = (bf16)(v.z * scale);
        o[3] = (bf16)(v.w * scale);
        *(bf16x4*)(Wf + (size_t)row * 512 + c4 * 4) = o;
      } else {
        int r = row - 1536;
#pragma unroll
        for (int e = 0; e < 4; ++e) {
          int c2 = c4 * 4 + e;
          Wor[(size_t)r * 512 + c2] =
              (bf16)Wo[(size_t)r * 512 + (c2 & 63) * 8 + (c2 >> 6)];
        }
      }
    }
    if (t < 8 && r0 + t < 1536) {
      int row = r0 + t;
      float bb;
      if (row < 512)       bb = bq[row] * SCALE_F;
      else if (row < 1024) bb = bk[row - 512];
      else                 bb = bv[row - 1024];
      biasf[row] = bb;
    }
  } else {
    int id2 = bid - 256;
    int n0 = (id2 & 31) * 64;
    int d0 = ((id2 >> 5) & 7) * 64;
    int b = id2 >> 8;
    int r = t >> 2, cw = t & 3;
    const float* src = Q + ((size_t)(b * 512 + d0 + r)) * 2048 + n0 + cw * 16;
#pragma unroll
    for (int e4 = 0; e4 < 4; ++e4) {
      float4 v = *(const float4*)(src + e4 * 4);
      tile[r][cw * 16 + e4 * 4 + 0] = v.x;
      tile[r][cw * 16 + e4 * 4 + 1] = v.y;
      tile[r][cw * 16 + e4 * 4 + 2] = v.z;
      tile[r][cw * 16 + e4 * 4 + 3] = v.w;
    }
    __syncthreads();
    bf16x8 o0{}, o1{};
#pragma unroll
    for (int e = 0; e < 8; ++e) {
      o0[e] = (bf16)tile[cw * 16 + e][r];
      o1[e] = (bf16)tile[cw * 16 + 8 + e][r];
    }
    bf16* dst = Qt + ((size_t)(b * 2048 + n0 + r)) * 512 + d0 + cw * 16;
    *(bf16x8*)dst = o0;
    *((bf16x8*)dst + 1) = o1;
  }
}

// ---------------------------------------------------------------------------
// qkv_gemm v5: v4 (BK=64, swizzled) + XCD chunk swizzle.
// 1-D grid 768; orig o = (h%8)*96 + h/8 -> the 12 c-tiles sharing a Qt
// strip are consecutive in o -> land on ONE XCD -> strip L2-hot.
// ---------------------------------------------------------------------------
__global__ __launch_bounds__(256) void qkv_gemm(
    const bf16* __restrict__ Wf, const bf16* __restrict__ Qt,
    const float* __restrict__ biasf,
    bf16* __restrict__ qp, bf16* __restrict__ kp, bf16* __restrict__ vn) {
  __shared__ bf16 Al[128 * 64];
  __shared__ bf16 Bl[64 * 64];
  int hbid = blockIdx.x;
  int o = (hbid & 7) * 96 + (hbid >> 3);
  int cx = o % 12;
  int py = (o / 12) & 31;
  int b = o / 384;
  int c0 = cx * 128;
  int p0 = py * 64;
  int tid = threadIdx.x, w = tid >> 6, lane = tid & 63;
  int wm = w >> 1, wn = w & 1;
  int g = lane >> 4, l15 = lane & 15;

  const bf16* Abase = Wf + (size_t)c0 * 512;
  const bf16* Bbase = Qt + ((size_t)b * 2048 + p0) * 512;

  int srow = tid >> 3;           // 0..31 (+i*32)
  int sch = tid & 7;

  f32x4 acc[4][2] = {};

  for (int ks = 0; ks < 8; ++ks) {
    int k0 = ks * 64;
    __syncthreads();
#pragma unroll
    for (int i = 0; i < 4; ++i) {
      int row = srow + i * 32;
      int ch = sch ^ (row & 7);
      gload_lds16(Abase + (size_t)row * 512 + k0 + ch * 8,
                  Al + (i * 32 + w * 8) * 64);
    }
#pragma unroll
    for (int i = 0; i < 2; ++i) {
      int row = srow + i * 32;
      int ch = sch ^ (row & 7);
      gload_lds16(Bbase + (size_t)row * 512 + k0 + ch * 8,
                  Bl + (i * 32 + w * 8) * 64);
    }
    __syncthreads();
#pragma unroll
    for (int ks2 = 0; ks2 < 2; ++ks2) {
      bf16x8 a[4], bb[2];
#pragma unroll
      for (int mi = 0; mi < 4; ++mi) {
        int row = wm * 64 + mi * 16 + l15;
        a[mi] = *(const bf16x8*)(Al + row * 64 +
                                 (((ks2 * 4 + g) ^ (row & 7)) << 3));
      }
#pragma unroll
      for (int ni = 0; ni < 2; ++ni) {
        int row = wn * 32 + ni * 16 + l15;
        bb[ni] = *(const bf16x8*)(Bl + row * 64 +
                                  (((ks2 * 4 + g) ^ (row & 7)) << 3));
      }
#pragma unroll
      for (int mi = 0; mi < 4; ++mi)
#pragma unroll
        for (int ni = 0; ni < 2; ++ni)
          acc[mi][ni] = mfma16(a[mi], bb[ni], acc[mi][ni]);
    }
  }

#pragma unroll
  for (int mi = 0; mi < 4; ++mi) {
#pragma unroll
    for (int ni = 0; ni < 2; ++ni) {
#pragma unroll
      for (int r = 0; r < 4; ++r) {
        int row = c0 + wm * 64 + mi * 16 + g * 4 + r;
        int p = p0 + wn * 32 + ni * 16 + l15;
        float val = acc[mi][ni][r] + biasf[row];
        bf16 hv = (bf16)val;
        if (row < 512) {
          int c = row;
          qp[(((size_t)b * 8 + (c & 7)) * 2048 + p) * 64 + (c >> 3)] = hv;
        } else if (row < 1024) {
          int c = row - 512;
          kp[(((size_t)b * 8 + (c & 7)) * 2048 + p) * 64 + (c >> 3)] = hv;
        } else {
          int c = row - 1024;
          vn[((size_t)b * 512 + c) * 2048 + p] = hv;
        }
      }
    }
  }
}

// ---------------------------------------------------------------------------
// attn_k v10: v9 + XCD chunk swizzle. 1-D grid 512; o = (h%8)*64 + h/8 ->
// the 8 q-tiles sharing one (bh,z) K/V slice (128KB) land on ONE XCD.
// ---------------------------------------------------------------------------
__global__ __launch_bounds__(512, 4) void attn_k(
    const bf16* __restrict__ qp, const bf16* __restrict__ kp,
    const bf16* __restrict__ vn, bf16* __restrict__ Op,
    float* __restrict__ mbuf, float* __restrict__ lbuf, int TS) {
  __shared__ bf16 Ks[2][64 * 64];
  __shared__ bf16 Vs[2][64 * 64];
  int hbid = blockIdx.x;
  int o = (hbid & 7) * 64 + (hbid >> 3);
  int q0 = (o & 7) * 256;
  int bh = (o >> 3) & 15;
  int z = o >> 7;
  int b = bh >> 3, h = bh & 7;
  int tid = threadIdx.x, w = tid >> 6, lane = tid & 63;
  int l31 = lane & 31, hi = lane >> 5;

  bf16x8 qreg[4];
#pragma unroll
  for (int kd = 0; kd < 4; ++kd)
    qreg[kd] = *(const bf16x8*)(
        qp + ((size_t)bh * 2048 + q0 + w * 32 + l31) * 64 + kd * 16 + hi * 8);

  int krow = tid >> 3;            // 0..63
  int kch = (tid & 7) ^ (krow & 7);

  const bf16* Kall = kp + (size_t)bh * 2048 * 64 + (size_t)z * TS * 4096;
  const bf16* Vall = vn + ((size_t)(b * 512 + h)) * 2048 + (size_t)z * TS * 64;

  gload_lds16(Kall + (size_t)krow * 64 + kch * 8, Ks[0] + w * 512);
  gload_lds16(Vall + (size_t)krow * 16384 + kch * 8, Vs[0] + w * 512);

  f32x16 oacc0 = {}, oacc1 = {};
  float mrow = -1e30f, rs = 0.0f;

  __syncthreads();

  for (int t = 0; t < TS; ++t) {
    int cur = t & 1, nxt = cur ^ 1;
    int tn = (t < TS - 1) ? t + 1 : t;

    gload_lds16(Kall + (size_t)tn * 4096 + (size_t)krow * 64 + kch * 8,
                Ks[nxt] + w * 512);
    gload_lds16(Vall + (size_t)tn * 64 + (size_t)krow * 16384 + kch * 8,
                Vs[nxt] + w * 512);

    f32x16 st0 = {}, st1 = {};
    __builtin_amdgcn_s_setprio(1);
#pragma unroll
    for (int kd = 0; kd < 4; ++kd) {
      int sw = ((kd * 2 + hi) ^ (l31 & 7)) << 3;
      bf16x8 kb0 = *(const bf16x8*)(Ks[cur] + l31 * 64 + sw);
      bf16x8 kb1 = *(const bf16x8*)(Ks[cur] + (32 + l31) * 64 + sw);
      st0 = mfma32(kb0, qreg[kd], st0);
      st1 = mfma32(kb1, qreg[kd], st1);
    }
    __builtin_amdgcn_s_setprio(0);

    float rm = st0[0];
#pragma unroll
    for (int r = 1; r < 16; ++r) rm = fmaxf(rm, st0[r]);
#pragma unroll
    for (int r = 0; r < 16; ++r) rm = fmaxf(rm, st1[r]);
    rm = fmaxf(rm, __shfl_xor(rm, 32));

    if (__any(rm > mrow + 8.0f)) {
      float nm = fmaxf(mrow, rm);
      float esc = __builtin_amdgcn_exp2f(mrow - nm);
      mrow = nm;
      rs *= esc;
#pragma unroll
      for (int r = 0; r < 16; ++r) {
        int ql = (r & 3) + 8 * (r >> 2) + 4 * hi;
        float er = __shfl(esc, ql, 64);
        oacc0[r] *= er;
        oacc1[r] *= er;
      }
    }

    bf16x8 pa[4];
#pragma unroll
    for (int tile = 0; tile < 2; ++tile) {
      float pv[16];
#pragma unroll
      for (int r = 0; r < 16; ++r) {
        float v = __builtin_amdgcn_exp2f((tile ? st1[r] : st0[r]) - mrow);
        pv[r] = v;
        rs += v;
      }
      unsigned int r0d0 = pkbf(pv[0], pv[1]),   r0d1 = pkbf(pv[2], pv[3]);
      unsigned int r1d0 = pkbf(pv[4], pv[5]),   r1d1 = pkbf(pv[6], pv[7]);
      unsigned int r2d0 = pkbf(pv[8], pv[9]),   r2d1 = pkbf(pv[10], pv[11]);
      unsigned int r3d0 = pkbf(pv[12], pv[13]), r3d1 = pkbf(pv[14], pv[15]);
      asm volatile("v_permlane32_swap_b32 %0, %1" : "+v"(r0d0), "+v"(r1d0));
      asm volatile("v_permlane32_swap_b32 %0, %1" : "+v"(r0d1), "+v"(r1d1));
      pa[tile * 2] = __builtin_bit_cast(bf16x8, (u32x4){r0d0, r0d1, r1d0, r1d1});
      asm volatile("v_permlane32_swap_b32 %0, %1" : "+v"(r2d0), "+v"(r3d0));
      asm volatile("v_permlane32_swap_b32 %0, %1" : "+v"(r2d1), "+v"(r3d1));
      pa[tile * 2 + 1] =
          __builtin_bit_cast(bf16x8, (u32x4){r2d0, r2d1, r3d0, r3d1});
    }

    __builtin_amdgcn_s_setprio(1);
#pragma unroll
    for (int kt = 0; kt < 4; ++kt) {
      int sw0 = ((kt * 2 + hi) ^ (l31 & 7)) << 3;
      bf16x8 vb0 = *(const bf16x8*)(Vs[cur] + l31 * 64 + sw0);
      bf16x8 vb1 = *(const bf16x8*)(Vs[cur] + (32 + l31) * 64 + sw0);
      oacc0 = mfma32(pa[kt], vb0, oacc0);
      oacc1 = mfma32(pa[kt], vb1, oacc1);
    }
    __builtin_amdgcn_s_setprio(0);

    __syncthreads();
  }

  rs += __shfl_xor(rs, 32);

  size_t zb = (size_t)(z * 16 + bh) * 2048 + q0 + w * 32;
#pragma unroll
  for (int r = 0; r < 16; ++r) {
    int ql = (r & 3) + 8 * (r >> 2) + 4 * hi;
    Op[(zb + ql) * 64 + l31] = (bf16)oacc0[r];
    Op[(zb + ql) * 64 + 32 + l31] = (bf16)oacc1[r];
  }
  if (hi == 0) {
    mbuf[zb + l31] = mrow;
    lbuf[zb + l31] = rs;
  }
}

// ---------------------------------------------------------------------------
// combine (unchanged): oh[row][d] = sum_z wz*O_z / sum_z wz*l_z.
// oh ALIASES Op[z=0] (each thread reads only its own slice -> race-free).
// ---------------------------------------------------------------------------
__global__ __launch_bounds__(256) void combine(
    const bf16* __restrict__ Op, const float* __restrict__ mbuf,
    const float* __restrict__ lbuf, bf16* __restrict__ oh, int NS) {
  int idx = blockIdx.x * 256 + threadIdx.x;
  int row = idx >> 2;
  int dc = (idx & 3) * 16;

  float M = -1e30f;
  for (int z = 0; z < NS; ++z) M = fmaxf(M, mbuf[(size_t)z * 32768 + row]);

  float L = 0.0f;
  float acc[16];
#pragma unroll
  for (int e = 0; e < 16; ++e) acc[e] = 0.0f;

  for (int z = 0; z < NS; ++z) {
    float wz = __builtin_amdgcn_exp2f(mbuf[(size_t)z * 32768 + row] - M);
    L += wz * lbuf[(size_t)z * 32768 + row];
    const bf16x8* p = (const bf16x8*)(Op + ((size_t)z * 32768 + row) * 64 + dc);
#pragma unroll
    for (int v = 0; v < 2; ++v) {
      bf16x8 x = p[v];
#pragma unroll
      for (int e = 0; e < 8; ++e) acc[v * 8 + e] += wz * (float)x[e];
    }
  }
  float invL = 1.0f / L;
  bf16x8* po = (bf16x8*)(oh + (size_t)row * 64 + dc);
#pragma unroll
  for (int v = 0; v < 2; ++v) {
    bf16x8 o;
#pragma unroll
    for (int e = 0; e < 8; ++e) o[e] = (bf16)(acc[v * 8 + e] * invL);
    po[v] = o;
  }
}

// ---------------------------------------------------------------------------
// out_gemm v5: v4 (BK=64, swizzled) + XCD chunk swizzle.
// 1-D grid 256; o = (h%8)*32 + h/8 -> the 4 r-tiles sharing a B strip
// land on ONE XCD.
// ---------------------------------------------------------------------------
__global__ __launch_bounds__(256) void out_gemm(
    const bf16* __restrict__ Wor, const bf16* __restrict__ oh,
    const float* __restrict__ bo, float* __restrict__ out) {
  __shared__ bf16 Al[128 * 64];
  __shared__ bf16 Bl[64 * 64];
  int hbid = blockIdx.x;
  int o = (hbid & 7) * 32 + (hbid >> 3);
  int r0 = (o & 3) * 128;
  int p0 = ((o >> 2) & 31) * 64;
  int b = o >> 7;
  int tid = threadIdx.x, w = tid >> 6, lane = tid & 63;
  int wm = w >> 1, wn = w & 1;
  int g = lane >> 4, l15 = lane & 15;

  const bf16* Abase = Wor + (size_t)r0 * 512;

  int srow = tid >> 3;
  int sch = tid & 7;

  f32x4 acc[4][2] = {};

  for (int ks = 0; ks < 8; ++ks) {
    int k0 = ks * 64;
    const bf16* Bbase = oh + (((size_t)b * 8 + ks) * 2048 + p0) * 64;
    __syncthreads();
#pragma unroll
    for (int i = 0; i < 4; ++i) {
      int row = srow + i * 32;
      int ch = sch ^ (row & 7);
      gload_lds16(Abase + (size_t)row * 512 + k0 + ch * 8,
                  Al + (i * 32 + w * 8) * 64);
    }
#pragma unroll
    for (int i = 0; i < 2; ++i) {
      int row = srow + i * 32;
      int ch = sch ^ (row & 7);
      gload_lds16(Bbase + (size_t)row * 64 + ch * 8,
                  Bl + (i * 32 + w * 8) * 64);
    }
    __syncthreads();
#pragma unroll
    for (int ks2 = 0; ks2 < 2; ++ks2) {
      bf16x8 a[4], bb[2];
#pragma unroll
      for (int mi = 0; mi < 4; ++mi) {
        int row = wm * 64 + mi * 16 + l15;
        a[mi] = *(const bf16x8*)(Al + row * 64 +
                                 (((ks2 * 4 + g) ^ (row & 7)) << 3));
      }
#pragma unroll
      for (int ni = 0; ni < 2; ++ni) {
        int row = wn * 32 + ni * 16 + l15;
        bb[ni] = *(const bf16x8*)(Bl + row * 64 +
                                  (((ks2 * 4 + g) ^ (row & 7)) << 3));
      }
#pragma unroll
      for (int mi = 0; mi < 4; ++mi)
#pragma unroll
        for (int ni = 0; ni < 2; ++ni)
          acc[mi][ni] = mfma16(a[mi], bb[ni], acc[mi][ni]);
    }
  }

#pragma unroll
  for (int mi = 0; mi < 4; ++mi) {
#pragma unroll
    for (int ni = 0; ni < 2; ++ni) {
#pragma unroll
      for (int r = 0; r < 4; ++r) {
        int row = r0 + wm * 64 + mi * 16 + g * 4 + r;
        int p = p0 + wn * 32 + ni * 16 + l15;
        out[((size_t)b * 512 + row) * 2048 + p] = acc[mi][ni][r] + bo[row];
      }
    }
  }
}

// ---------------------------------------------------------------------------
extern "C" void kernel_launch(void* const* d_in, const int* in_sizes, int n_in,
                              void* d_out, int out_size, void* d_ws, size_t ws_size,
                              hipStream_t stream) {
  (void)in_sizes; (void)n_in; (void)out_size;
  const float* Q  = (const float*)d_in[0];
  const float* Wq = (const float*)d_in[1];
  const float* bq = (const float*)d_in[2];
  const float* Wk = (const float*)d_in[3];
  const float* bk = (const float*)d_in[4];
  const float* Wv = (const float*)d_in[5];
  const float* bv = (const float*)d_in[6];
  const float* Wo = (const float*)d_in[7];
  const float* bo = (const float*)d_in[8];
  float* out = (float*)d_out;

  char* ws = (char*)d_ws;
  bf16*  Wf    = (bf16*)(ws + 0);          // 1536*512*2  = 1572864
  bf16*  Wor   = (bf16*)(ws + 1572864);    // 512*512*2   = 524288
  float* biasf = (float*)(ws + 2097152);   // 1536*4      = 6144
  bf16*  Qt    = (bf16*)(ws + 2103296);    // 2*2048*512*2 = 4194304
  bf16*  qp    = (bf16*)(ws + 6297600);    // 4194304
  bf16*  kp    = (bf16*)(ws + 10491904);   // 4194304
  bf16*  vn    = (bf16*)(ws + 14686208);   // 4194304 (ends 18880512)

  size_t need4 = 18880512ull + 4ull * 4194304 + 2ull * 4ull * 131072;
  int NS = (ws_size >= need4) ? 4 : 2;
  int TS = 32 / NS;

  bf16*  Opart = (bf16*)(ws + 18880512);               // NS * 4194304 bytes
  float* mbuf  = (float*)(ws + 18880512 + (size_t)NS * 4194304);
  float* lbuf  = (float*)(ws + 18880512 + (size_t)NS * 4194304 +
                          (size_t)NS * 131072);
  bf16*  oh    = Opart;  // combine writes in place over z=0 (race-free)

  prep<<<dim3(768), dim3(256), 0, stream>>>(Q, Wq, bq, Wk, bk, Wv, bv, Wo,
                                            Wf, biasf, Wor, Qt);
  qkv_gemm<<<dim3(768), dim3(256), 0, stream>>>(Wf, Qt, biasf, qp, kp, vn);
  attn_k<<<dim3(16 * NS * 8), dim3(512), 0, stream>>>(qp, kp, vn, Opart, mbuf,
                                                      lbuf, TS);
  combine<<<dim3(512), dim3(256), 0, stream>>>(Opart, mbuf, lbuf, oh, NS);
  out_gemm<<<dim3(256), dim3(256), 0, stream>>>(Wor, oh, bo, out);
}